// Round 14
// baseline (459.299 us; speedup 1.0000x reference)
//
#include <hip/hip_runtime.h>

// Problem constants
#define B_   512
#define T_   128
#define D_   384
#define H_   6
#define DH_  64
#define DFF_ 1536
#define NROW (B_*T_)   // 65536 rows

typedef __attribute__((ext_vector_type(8))) short bf16x8;    // MFMA A/B frag (4 VGPRs)
typedef __attribute__((ext_vector_type(4))) float f32x4;     // 16x16 C/D frag
typedef __attribute__((ext_vector_type(16))) float f32x16;   // 32x32 C/D frag

__device__ __forceinline__ unsigned short f2bf(float f) {
  union { float f; unsigned u; } v; v.f = f;
  unsigned r = v.u + 0x7fffu + ((v.u >> 16) & 1u);   // RNE
  return (unsigned short)(r >> 16);
}

// async global->LDS, 16 B per lane, wave-uniform LDS base (m97 pattern)
#define GLDS16(gp, lp)                                                     \
  __builtin_amdgcn_global_load_lds(                                        \
      (const __attribute__((address_space(1))) void*)(gp),                 \
      (__attribute__((address_space(3))) void*)(lp), 16, 0, 0)

// lgkm-only barrier (keeps reg-destined global loads in flight)
#define BAR_LGKM() asm volatile("s_waitcnt lgkmcnt(0)\n\ts_barrier" ::: "memory")

// ---------------- weight transpose + fp32->bf16 convert ----------------
__global__ void wt_kernel(const float* __restrict__ W, unsigned short* __restrict__ WT,
                          int K, int Nn) {
  int id = blockIdx.x * 256 + threadIdx.x;
  if (id >= K * Nn) return;
  int n = id % Nn, kk = id / Nn;               // coalesced read along n
  WT[(size_t)n * K + kk] = f2bf(W[(size_t)kk * Nn + n]);
}

// ---------------- W1 packing for 32x32x16 A-frags -------------------------
// frag=(c6*8+w)*24+k16 ; lane 16B = W1T[c6*256+w*32+(lane&31)][k16*16+(lane>>5)*8]
__global__ void pack_w1_32(const unsigned short* __restrict__ W1T,  // [1536][384]
                           unsigned short* __restrict__ W1P) {
  int tid = blockIdx.x * 256 + threadIdx.x;      // 73728 16B-chunks (288 blocks)
  int lane = tid & 63, frag = tid >> 6;
  int k16 = frag % 24, t = frag / 24;
  int w = t & 7, c6 = t >> 3;
  int row = c6 * 256 + w * 32 + (lane & 31);
  int col = k16 * 16 + (lane >> 5) * 8;
  *(int4*)(W1P + (size_t)tid * 8) = *(const int4*)(W1T + (size_t)row * 384 + col);
}
// W2 (K=1536): frag=(((w4*6+mi6)*12+c)*4+kk)  (R9-verified 16x16 pack)
__global__ void pack_w2(const unsigned short* __restrict__ W2T,  // [384][1536]
                        unsigned short* __restrict__ W2P) {
  int tid = blockIdx.x * 256 + threadIdx.x;      // 73728 16B-chunks (288 blocks)
  int lane = tid & 63, frag = tid >> 6;
  int kk = frag & 3, t2 = frag >> 2;
  int c = t2 % 12, t3 = t2 / 12;
  int mi = t3 % 6, w = t3 / 6;
  int l15 = lane & 15, lq = lane >> 4;
  int r = w * 96 + mi * 16 + l15;
  int col = c * 128 + kk * 32 + lq * 8;
  *(int4*)(W2P + (size_t)tid * 8) = *(const int4*)(W2T + (size_t)r * 1536 + col);
}

// ---------------- layernorm: fp32 in -> bf16 out (one wave per row) ----------------
__global__ __launch_bounds__(256) void ln_kernel(const float* __restrict__ x,
                                                 const float* __restrict__ g,
                                                 const float* __restrict__ be,
                                                 unsigned short* __restrict__ out) {
  int row = (blockIdx.x * 256 + threadIdx.x) >> 6;
  int l = threadIdx.x & 63;
  const float* xr = x + (size_t)row * D_;
  float v[6]; float s = 0.f, ss = 0.f;
  #pragma unroll
  for (int i = 0; i < 6; ++i) { v[i] = xr[l + i*64]; s += v[i]; ss += v[i]*v[i]; }
  #pragma unroll
  for (int m = 1; m < 64; m <<= 1) { s += __shfl_xor(s, m); ss += __shfl_xor(ss, m); }
  float mu  = s * (1.f / D_);
  float var = ss * (1.f / D_) - mu * mu;
  float rs  = rsqrtf(var + 1e-5f);
  unsigned short* orow = out + (size_t)row * D_;
  #pragma unroll
  for (int i = 0; i < 6; ++i) {
    int c = l + i*64;
    orow[c] = f2bf((v[i] - mu) * rs * g[c] + be[c]);
  }
}

// ---------------- NT GEMM (QKV / Wo): 2-phase dbuf, gload_lds (R9-proven) ----------
template<int EPI>
__global__ __launch_bounds__(256) void gemm_bt(const unsigned short* __restrict__ A,
                                               const unsigned short* __restrict__ BT,
                                               void* __restrict__ Cc,
                                               const float* __restrict__ bias,
                                               const float* __restrict__ res,
                                               int Nn, int K) {
  __shared__ unsigned short As[2][128][32];
  __shared__ unsigned short Bs[2][128][32];
  int tid = threadIdx.x, w = tid >> 6, l = tid & 63;
  int wr = w >> 1, wc = w & 1;
  size_t R0 = (size_t)blockIdx.x * 128;
  int C0 = blockIdx.y * 128;

  int seg0 = (w * 2 + 0) * 16;
  int seg1 = (w * 2 + 1) * 16;
  int srow0 = seg0 + (l >> 2);
  int srow1 = seg1 + (l >> 2);
  int scol  = (l & 3) * 8;

  const unsigned short* ga0 = A  + (R0 + srow0) * K + scol;
  const unsigned short* ga1 = A  + (R0 + srow1) * K + scol;
  const unsigned short* gb0 = BT + (size_t)(C0 + srow0) * K + scol;
  const unsigned short* gb1 = BT + (size_t)(C0 + srow1) * K + scol;

  f32x4 acc[4][4];
  #pragma unroll
  for (int i = 0; i < 4; ++i)
    #pragma unroll
    for (int j = 0; j < 4; ++j) acc[i][j] = (f32x4){0.f, 0.f, 0.f, 0.f};

  GLDS16(ga0, &As[0][seg0][0]);
  GLDS16(ga1, &As[0][seg1][0]);
  GLDS16(gb0, &Bs[0][seg0][0]);
  GLDS16(gb1, &Bs[0][seg1][0]);
  ga0 += 32; ga1 += 32; gb0 += 32; gb1 += 32;

  int nk = K >> 5;
  for (int t = 0; t < nk; ++t) {
    int cur = t & 1;
    __syncthreads();
    if (t + 1 < nk) {
      GLDS16(ga0, &As[cur ^ 1][seg0][0]);
      GLDS16(ga1, &As[cur ^ 1][seg1][0]);
      GLDS16(gb0, &Bs[cur ^ 1][seg0][0]);
      GLDS16(gb1, &Bs[cur ^ 1][seg1][0]);
      ga0 += 32; ga1 += 32; gb0 += 32; gb1 += 32;
    }
    bf16x8 af[4], bf[4];
    #pragma unroll
    for (int mi = 0; mi < 4; ++mi)
      af[mi] = *(const bf16x8*)(&As[cur][wr*64 + mi*16 + (l & 15)][(l >> 4) * 8]);
    #pragma unroll
    for (int ni = 0; ni < 4; ++ni)
      bf[ni] = *(const bf16x8*)(&Bs[cur][wc*64 + ni*16 + (l & 15)][(l >> 4) * 8]);
    #pragma unroll
    for (int mi = 0; mi < 4; ++mi)
      #pragma unroll
      for (int ni = 0; ni < 4; ++ni)
        acc[mi][ni] = __builtin_amdgcn_mfma_f32_16x16x32_bf16(af[mi], bf[ni], acc[mi][ni], 0, 0, 0);
  }

  #pragma unroll
  for (int mi = 0; mi < 4; ++mi) {
    #pragma unroll
    for (int ni = 0; ni < 4; ++ni) {
      int col = C0 + wc*64 + ni*16 + (l & 15);
      #pragma unroll
      for (int j = 0; j < 4; ++j) {
        size_t row = R0 + wr*64 + mi*16 + ((l >> 4) << 2) + j;
        float vv = acc[mi][ni][j];
        if (EPI == 1) {
          ((float*)Cc)[row * Nn + col] = vv + bias[col] + res[row * Nn + col];
        } else {
          int buf = col / 384, c2 = col - buf * 384;
          ((unsigned short*)Cc)[(size_t)buf * NROW * 384 + row * 384 + c2] = f2bf(vv);
        }
      }
    }
  }
}

// ---------------- fused FFN v2: 32x32 P-phase, 256-col chunks, 80KB dyn LDS --------
// LDS: h2f 32x32-B-frag order @0 (48KB): frag(nt,k16)=(nt*24+k16)*1024 + lane*16
//        holds h2[nt*32+(l&31)][k16*16+(l>>5)*8 ..+7]
//      Psf 16x16-B-frag order @49152 (32KB): frag(ni,kk)=(ni*8+kk)*1024 + lane*16
//        holds P[ni*16+l15][kk*32+lq*8 ..+7]  (kk in 8 x 32-col steps of the 256 chunk)
// P:  wave w owns chunk ffcols w*32..+31 (one 32x32 m-tile), 24 k16-steps, 1:1 read:MFMA
//     but each MFMA is 32768 FLOP -> LDS bytes/FLOP halved vs 16x16 single-m.
// PV: 16x16, 8 kk-steps, wave w owns out cols w*48..+47 (3 m-tiles).
__global__ __launch_bounds__(512, 4) void ffn_fused(
    const unsigned short* __restrict__ h2,   // [NROW][384] bf16
    const unsigned short* __restrict__ w1P,  // packed (pack_w1_32)
    const unsigned short* __restrict__ w2P,  // packed (pack_w2)
    const float* __restrict__ b1,            // [1536]
    const float* __restrict__ b2,            // [384]
    float* __restrict__ out)                 // [NROW][384] fp32, in-place residual add
{
  extern __shared__ __align__(16) char smem[];   // 81920 B
  int tid = threadIdx.x, w = tid >> 6, l = tid & 63;
  int l15 = l & 15, lq = l >> 4;
  size_t R0 = (size_t)blockIdx.x * 64;

  // ---- stage h2 strip -> 32x32 B-frag LDS (512 thr x 48 elems) ----
  {
    int row = tid >> 3, nt = row >> 5, r31 = row & 31;
    const unsigned short* src = h2 + (R0 + row) * 384;
    #pragma unroll
    for (int i = 0; i < 6; ++i) {
      int c8 = (tid & 7) + i * 8;              // 8-short chunk index (0..47)
      int k16 = c8 >> 1, hi = c8 & 1;
      *(int4*)(smem + (nt*24 + k16)*1024 + (hi*32 + r31)*16) =
          *(const int4*)(src + c8 * 8);
    }
  }
  __syncthreads();

  f32x4 oacc[3][4];
  #pragma unroll
  for (int i = 0; i < 3; ++i)
    #pragma unroll
    for (int j = 0; j < 4; ++j) oacc[i][j] = (f32x4){0.f, 0.f, 0.f, 0.f};

  const unsigned short* w1b = w1P + w * 12288 + l * 8;  // + c*98304 + k16*512
  const unsigned short* w2b = w2P + w * 73728 + l * 8;  // + mi*24576 + c*4096 + kkterm

  for (int c = 0; c < 6; ++c) {
    const unsigned short* pA = w1b + (size_t)c * 98304;
    const unsigned short* pV = w2b + c * 4096;

    f32x16 pacc[2];
    pacc[0] = (f32x16)(0.f);
    pacc[1] = (f32x16)(0.f);

    // ---- P-phase: 24 k16-steps in 6 groups of 4; 2 x 32x32 MFMA per step ----
    #pragma unroll
    for (int g = 0; g < 6; ++g) {
      bf16x8 af[4];
      #pragma unroll
      for (int kq = 0; kq < 4; ++kq)
        af[kq] = *(const bf16x8*)(pA + (g*4 + kq) * 512);
      __builtin_amdgcn_s_setprio(1);
      #pragma unroll
      for (int kq = 0; kq < 4; ++kq) {
        bf16x8 b0 = *(const bf16x8*)(smem + ((g*4 + kq))*1024 + l*16);
        bf16x8 b1f = *(const bf16x8*)(smem + (24 + g*4 + kq)*1024 + l*16);
        pacc[0] = __builtin_amdgcn_mfma_f32_32x32x16_bf16(af[kq], b0,  pacc[0], 0, 0, 0);
        pacc[1] = __builtin_amdgcn_mfma_f32_32x32x16_bf16(af[kq], b1f, pacc[1], 0, 0, 0);
      }
      __builtin_amdgcn_s_setprio(0);
    }

    // ---- P epilogue: bias1 + relu + bf16 pack -> Psf (16x16 B-frag layout) ----
    // pacc[nt][reg]: row(h2)=nt*32+(l&31), ffcol-in-32 = (reg&3)+8*(reg>>2)+4*(l>>5)
    {
      int hi = l >> 5, r31 = l & 31;
      int niB = r31 >> 4;                       // +2*nt below
      #pragma unroll
      for (int nt = 0; nt < 2; ++nt) {
        int ni = nt*2 + niB;
        #pragma unroll
        for (int q = 0; q < 4; ++q) {
          int fcb = c * 256 + w * 32 + q * 8 + hi * 4;
          float4 bb = *(const float4*)(b1 + fcb);
          float p0 = ((nt == 0) ? pacc[0][q*4+0] : pacc[1][q*4+0]) + bb.x;
          float p1 = ((nt == 0) ? pacc[0][q*4+1] : pacc[1][q*4+1]) + bb.y;
          float p2 = ((nt == 0) ? pacc[0][q*4+2] : pacc[1][q*4+2]) + bb.z;
          float p3 = ((nt == 0) ? pacc[0][q*4+3] : pacc[1][q*4+3]) + bb.w;
          ushort4 pk;
          pk.x = f2bf(p0 > 0.f ? p0 : 0.f);
          pk.y = f2bf(p1 > 0.f ? p1 : 0.f);
          pk.z = f2bf(p2 > 0.f ? p2 : 0.f);
          pk.w = f2bf(p3 > 0.f ? p3 : 0.f);
          *(ushort4*)(smem + 49152 + (ni*8 + w)*1024 + (q*16 + l15)*16 + hi*8) = pk;
        }
      }
    }
    BAR_LGKM();   // P writes drained; PV may read

    // ---- PV: 8 kk-steps (K=256), 16x16, 3 m-tiles x 4 ni per step ----
    #pragma unroll
    for (int kk = 0; kk < 8; ++kk) {
      bf16x8 av[3];
      #pragma unroll
      for (int mi = 0; mi < 3; ++mi)
        av[mi] = *(const bf16x8*)(pV + mi*24576 + (kk>>2)*2048 + (kk&3)*512);
      bf16x8 bv[4];
      #pragma unroll
      for (int ni = 0; ni < 4; ++ni)
        bv[ni] = *(const bf16x8*)(smem + 49152 + (ni*8 + kk)*1024 + l*16);
      __builtin_amdgcn_s_setprio(1);
      #pragma unroll
      for (int mi = 0; mi < 3; ++mi)
        #pragma unroll
        for (int ni = 0; ni < 4; ++ni)
          oacc[mi][ni] = __builtin_amdgcn_mfma_f32_16x16x32_bf16(av[mi], bv[ni], oacc[mi][ni], 0, 0, 0);
      __builtin_amdgcn_s_setprio(0);
    }
    BAR_LGKM();   // PV reads retired before next chunk overwrites Psf
  }

  // epilogue: out[row][ocol..+3] = oacc + b2 + res  (dwordx4)
  #pragma unroll
  for (int mi = 0; mi < 3; ++mi) {
    int ocb = w * 48 + mi * 16 + lq * 4;
    float4 b2v = *(const float4*)(b2 + ocb);
    #pragma unroll
    for (int ni = 0; ni < 4; ++ni) {
      size_t row = R0 + ni * 16 + l15;
      float* op = out + row * D_ + ocb;
      float4 r = *(const float4*)op;
      float4 o;
      o.x = oacc[mi][ni][0] + b2v.x + r.x;
      o.y = oacc[mi][ni][1] + b2v.y + r.y;
      o.z = oacc[mi][ni][2] + b2v.z + r.z;
      o.w = oacc[mi][ni][3] + b2v.w + r.w;
      *(float4*)op = o;
    }
  }
}

// ---------------- causal attention (+T5 setprio), one block per (b,h) ----------------
__global__ __launch_bounds__(256) void attn_kernel(const unsigned short* __restrict__ q,
                                                   const unsigned short* __restrict__ k,
                                                   const unsigned short* __restrict__ v,
                                                   unsigned short* __restrict__ o) {
  __shared__ __align__(16) char smem[52224];
  unsigned short (*Ks)[72]       = (unsigned short(*)[72])smem;
  unsigned short (*Ps)[32][136]  = (unsigned short(*)[32][136])smem;
  unsigned short (*Vt)[136]      = (unsigned short(*)[136])(smem + 34816);

  int bh = blockIdx.x;
  int b = bh / H_, h = bh % H_;
  int tid = threadIdx.x, w = tid >> 6, l = tid & 63;

  const unsigned short* kb = k + ((size_t)b * T_) * D_ + h * DH_;
  const unsigned short* vb = v + ((size_t)b * T_) * D_ + h * DH_;
  #pragma unroll
  for (int it = 0; it < 4; ++it) {
    int id = it * 256 + tid;
    int s = id >> 3, c8 = (id & 7) * 8;
    int4 kv = *(const int4*)(kb + (size_t)s * D_ + c8);
    *(int4*)(&Ks[s][c8]) = kv;
    int4 vv = *(const int4*)(vb + (size_t)s * D_ + c8);
    const unsigned short* pe = (const unsigned short*)&vv;
    #pragma unroll
    for (int j2 = 0; j2 < 8; ++j2) Vt[c8 + j2][s] = pe[j2];
  }
  __syncthreads();

  const unsigned short* qbp = q + ((size_t)b * T_) * D_ + h * DH_;
  int rowbase = w * 32;
  bf16x8 aq[2][2];
  #pragma unroll
  for (int mi = 0; mi < 2; ++mi)
    #pragma unroll
    for (int ks = 0; ks < 2; ++ks)
      aq[mi][ks] = *(const bf16x8*)(qbp + (size_t)(rowbase + mi*16 + (l & 15)) * D_
                                        + ks*32 + ((l >> 4) << 3));

  f32x4 accs[2][8];
  #pragma unroll
  for (int i = 0; i < 2; ++i)
    #pragma unroll
    for (int j = 0; j < 8; ++j) accs[i][j] = (f32x4){0.f, 0.f, 0.f, 0.f};
  #pragma unroll
  for (int ks = 0; ks < 2; ++ks) {
    bf16x8 bk[8];
    #pragma unroll
    for (int ni = 0; ni < 8; ++ni)
      bk[ni] = *(const bf16x8*)(&Ks[ni*16 + (l & 15)][ks*32 + ((l >> 4) << 3)]);
    __builtin_amdgcn_s_setprio(1);
    #pragma unroll
    for (int mi = 0; mi < 2; ++mi)
      #pragma unroll
      for (int ni = 0; ni < 8; ++ni)
        accs[mi][ni] = __builtin_amdgcn_mfma_f32_16x16x32_bf16(aq[mi][ks], bk[ni], accs[mi][ni], 0, 0, 0);
    __builtin_amdgcn_s_setprio(0);
  }
  __syncthreads();

  #pragma unroll
  for (int mi = 0; mi < 2; ++mi) {
    #pragma unroll
    for (int j = 0; j < 4; ++j) {
      int t = rowbase + mi*16 + ((l >> 4) << 2) + j;
      float mx = -1e30f;
      #pragma unroll
      for (int ni = 0; ni < 8; ++ni) {
        int scol = ni*16 + (l & 15);
        float sv = accs[mi][ni][j] * 0.125f;
        sv = (scol <= t) ? sv : -1e30f;
        accs[mi][ni][j] = sv;
        mx = fmaxf(mx, sv);
      }
      mx = fmaxf(mx, __shfl_xor(mx, 1));
      mx = fmaxf(mx, __shfl_xor(mx, 2));
      mx = fmaxf(mx, __shfl_xor(mx, 4));
      mx = fmaxf(mx, __shfl_xor(mx, 8));
      float sum = 0.f;
      #pragma unroll
      for (int ni = 0; ni < 8; ++ni) {
        float e = __expf(accs[mi][ni][j] - mx);
        accs[mi][ni][j] = e;
        sum += e;
      }
      sum += __shfl_xor(sum, 1);
      sum += __shfl_xor(sum, 2);
      sum += __shfl_xor(sum, 4);
      sum += __shfl_xor(sum, 8);
      float inv = 1.f / sum;
      #pragma unroll
      for (int ni = 0; ni < 8; ++ni)
        Ps[w][mi*16 + ((l >> 4) << 2) + j][ni*16 + (l & 15)] = f2bf(accs[mi][ni][j] * inv);
    }
  }
  __syncthreads();

  f32x4 acco[2][4];
  #pragma unroll
  for (int i = 0; i < 2; ++i)
    #pragma unroll
    for (int j = 0; j < 4; ++j) acco[i][j] = (f32x4){0.f, 0.f, 0.f, 0.f};
  #pragma unroll
  for (int ks = 0; ks < 4; ++ks) {
    bf16x8 ap[2], bv[4];
    #pragma unroll
    for (int mi = 0; mi < 2; ++mi)
      ap[mi] = *(const bf16x8*)(&Ps[w][mi*16 + (l & 15)][ks*32 + ((l >> 4) << 3)]);
    #pragma unroll
    for (int ni = 0; ni < 4; ++ni)
      bv[ni] = *(const bf16x8*)(&Vt[ni*16 + (l & 15)][ks*32 + ((l >> 4) << 3)]);
    __builtin_amdgcn_s_setprio(1);
    #pragma unroll
    for (int mi = 0; mi < 2; ++mi)
      #pragma unroll
      for (int ni = 0; ni < 4; ++ni)
        acco[mi][ni] = __builtin_amdgcn_mfma_f32_16x16x32_bf16(ap[mi], bv[ni], acco[mi][ni], 0, 0, 0);
    __builtin_amdgcn_s_setprio(0);
  }

  unsigned short* ob = o + ((size_t)b * T_) * D_ + h * DH_;
  #pragma unroll
  for (int mi = 0; mi < 2; ++mi)
    #pragma unroll
    for (int ni = 0; ni < 4; ++ni)
      #pragma unroll
      for (int j = 0; j < 4; ++j) {
        int t = rowbase + mi*16 + ((l >> 4) << 2) + j;
        int d = ni*16 + (l & 15);
        ob[(size_t)t * D_ + d] = f2bf(acco[mi][ni][j]);
      }
}

extern "C" void kernel_launch(void* const* d_in, const int* in_sizes, int n_in,
                              void* d_out, int out_size, void* d_ws, size_t ws_size,
                              hipStream_t stream) {
  const float* x   = (const float*)d_in[0];
  const float* Wq  = (const float*)d_in[1];
  const float* Wk  = (const float*)d_in[2];
  const float* Wv  = (const float*)d_in[3];
  const float* Wo  = (const float*)d_in[4];
  const float* bo  = (const float*)d_in[5];
  const float* W1  = (const float*)d_in[6];
  const float* b1  = (const float*)d_in[7];
  const float* W2  = (const float*)d_in[8];
  const float* b2  = (const float*)d_in[9];
  const float* g1  = (const float*)d_in[10];
  const float* be1 = (const float*)d_in[11];
  const float* g2  = (const float*)d_in[12];
  const float* be2 = (const float*)d_in[13];

  // workspace layout (bytes); total ~207 MiB  (R9 layout)
  char* ws = (char*)d_ws;
  unsigned short* hb   = (unsigned short*)(ws);               // h (LN1), later h2 (LN2)
  unsigned short* qb   = (unsigned short*)(ws +  50331648);   // q|k|v contiguous; o in-place
  unsigned short* kbuf = (unsigned short*)(ws + 100663296);
  unsigned short* vbuf = (unsigned short*)(ws + 150994944);
  unsigned short* wqT  = (unsigned short*)(ws + 201326592);   // [1152][384] (wq|wk|wv)
  unsigned short* wkT  = wqT + 147456;
  unsigned short* wvT  = wkT + 147456;
  unsigned short* woT  = wvT + 147456;                        // [384][384]
  unsigned short* w1T  = woT + 147456;                        // [1536][384]
  unsigned short* w2T  = w1T + 589824;                        // [384][1536]
  unsigned short* w1P  = w2T + 589824;                        // packed 32x32 frag-order
  unsigned short* w2P  = w1P + 589824;
  float* x2 = (float*)d_out;
  (void)kbuf; (void)vbuf;

  // allow 80KB dynamic LDS for ffn_fused (host-side attribute; not stream-ordered)
  static bool attr_set = false;
  if (!attr_set) {
    hipFuncSetAttribute(reinterpret_cast<const void*>(ffn_fused),
                        hipFuncAttributeMaxDynamicSharedMemorySize, 81920);
    attr_set = true;
  }

  // 1) weight convert+transpose (tiny) + fragment-order packs (FFN weights)
  wt_kernel<<<dim3(576),  256, 0, stream>>>(Wq, wqT, 384, 384);
  wt_kernel<<<dim3(576),  256, 0, stream>>>(Wk, wkT, 384, 384);
  wt_kernel<<<dim3(576),  256, 0, stream>>>(Wv, wvT, 384, 384);
  wt_kernel<<<dim3(576),  256, 0, stream>>>(Wo, woT, 384, 384);
  wt_kernel<<<dim3(2304), 256, 0, stream>>>(W1, w1T, 384, 1536);
  wt_kernel<<<dim3(2304), 256, 0, stream>>>(W2, w2T, 1536, 384);
  pack_w1_32<<<dim3(288), 256, 0, stream>>>(w1T, w1P);
  pack_w2<<<dim3(288), 256, 0, stream>>>(w2T, w2P);

  // 2) LN1: x -> h (bf16)
  ln_kernel<<<dim3(NROW / 4), 256, 0, stream>>>(x, g1, be1, hb);

  // 3) fused q|k|v = h @ [Wq|Wk|Wv]  (N=1152, split-store epilogue; R9-proven)
  gemm_bt<3><<<dim3(NROW / 128, 9), 256, 0, stream>>>(hb, wqT, qb, nullptr, nullptr, 1152, 384);

  // 4) attention: o overwrites q in place (per-block disjoint strips)
  attn_kernel<<<dim3(B_ * H_), 256, 0, stream>>>(qb, kbuf, vbuf, qb);

  // 5) x2 = x + o @ Wo + bo   (fp32, into d_out; R9-proven)
  gemm_bt<1><<<dim3(NROW / 128, 3), 256, 0, stream>>>(qb, woT, x2, bo, x, 384, 384);

  // 6) LN2: x2 -> h2 (bf16, into hb)
  ln_kernel<<<dim3(NROW / 4), 256, 0, stream>>>((const float*)x2, g2, be2, hb);

  // 7) fused FFN v2 (32x32 P, 256-col chunks, 80KB dyn LDS)
  ffn_fused<<<dim3(NROW / 64), 512, 81920, stream>>>(hb, w1P, w2P, b1, b2, x2);
}